// Round 6
// baseline (6742.108 us; speedup 1.0000x reference)
//
#include <hip/hip_runtime.h>
#include <math.h>

#define HDIM 1024
#define BDIM 64
#define TDIM 512
#define KIN  128
#define NBLK 256
#define NTHR 1024           // 16 waves
#define FRAME (HDIM * BDIM) // halfs per ring frame (2-deep rings)
#define SUBF  (HDIM * 32)   // halfs per 32-batch subframe

typedef _Float16 f16;
typedef __attribute__((ext_vector_type(2))) _Float16 f16x2;
typedef __attribute__((ext_vector_type(8))) _Float16 f16x8;
typedef __attribute__((ext_vector_type(4))) float f32x4;
typedef __attribute__((ext_vector_type(2))) unsigned u32x2;
typedef __attribute__((ext_vector_type(4))) unsigned u32x4;

#define MFMA16(a, b, c) __builtin_amdgcn_mfma_f32_16x16x32_f16((a), (b), (c), 0, 0, 0)

__device__ __forceinline__ float sigm(float x) { return 1.0f / (1.0f + expf(-x)); }

// ---------------------------------------------------------------------------
// r14: SINGLE-STAGE MERGED BODY on the r12 tiling (256 blocks = 128 cg x 2 bg;
// block owns 8 cols x 32 batches; 16 waves; 16-way K-split).
// r13 post-mortem: step time = max(latency-chain, BW). We are latency-bound
// at ~6us/step because r12's body serializes two phase-legs (2 polls, 2
// vmcnt(0) exposures, 2 fold+reduce passes, 2 publishes, 7 barriers).
// r14 merges them: concurrent polls -> 1 barrier -> ALL loads (A1+A2+x, one
// vmcnt(0)) -> all MFMAs -> one 64-slot fold (write/add, 2 barriers) ->
// PARALLEL owner reduces (waves 0-3: h1, waves 4-7: h2) -> 1 barrier ->
// PARALLEL publishes (wave8: ring1+tagA, wave9: ring2+tagB).
// Subframe layout (halfs): idx(k, b32) = (k>>3)*256 + b32*8 + (k&7).
// All ring I/O sc0sc1 (L3 coherence point; r11 showed cached+inv is 6x worse).
// Tags: tagA[bid], tagB[bid], bid = bg*128+cg -> same-bg tags contiguous;
// poll reads 128 tags via 64 lanes x dwordx2.
// Step semantics (identical to r12): at step s compute h1^(s) (from h1^(s-1),
// x_s) and h2^(s-1) (from h1^(s-1), h2^(s-2)).
//   top of s: tagA >= s+1 (h1^(s-1)), tagB >= s (h2^(s-2)).
//   publish h1^(s) -> tagA=s+2; publish h2^(s-1) -> tagB=s+1.
// ---------------------------------------------------------------------------
__device__ __forceinline__ f16x8 ld_cg(const f16* p) {
    f16x8 r;
    asm volatile("global_load_dwordx4 %0, %1, off sc0 sc1"
                 : "=v"(r) : "v"(p) : "memory");
    return r;
}
__device__ __forceinline__ void st_cg8(f16* p, uint2 v) {
    asm volatile("global_store_dwordx2 %0, %1, off sc0 sc1"
                 :: "v"(p), "v"(v) : "memory");
}
#define VM_DRAIN() asm volatile("s_waitcnt vmcnt(0)" ::: "memory")
// all VMEM done + no MFMA hoisting above the wait (guide rule #18)
#define VM_WAIT_ALL()                                                    \
    do {                                                                 \
        asm volatile("s_waitcnt vmcnt(0)" ::: "memory");                 \
        __builtin_amdgcn_sched_barrier(0);                               \
    } while (0)

__device__ __forceinline__ void tag_pub(unsigned* tag, unsigned v) {
    asm volatile("global_store_dword %0, %1, off sc0 sc1"
                 :: "v"(tag), "v"(v) : "memory");
}
// poll 128 contiguous tags (one bg stream): 64 lanes x dwordx2
__device__ __forceinline__ void tag_poll128(const unsigned* tags, int lane,
                                            unsigned tgt) {
    const unsigned* p = tags + lane * 2;
    for (;;) {
        u32x2 t;
        asm volatile("global_load_dwordx2 %0, %1, off sc0 sc1\n\t"
                     "s_waitcnt vmcnt(0)"
                     : "=v"(t) : "v"(p) : "memory");
        bool ok = (t.x >= tgt) && (t.y >= tgt);
        if (__all(ok)) break;
        __builtin_amdgcn_s_sleep(1);
    }
}

// ---------------------------------------------------------------------------
__global__ void cvt_w(const float* __restrict__ src, f16* __restrict__ dst, int n2) {
    int i = blockIdx.x * blockDim.x + threadIdx.x;
    if (i < n2) {
        float2 a = ((const float2*)src)[i];
        f16x2 o = {(f16)a.x, (f16)a.y};
        ((f16x2*)dst)[i] = o;
    }
}

// x[b][t][k] fp32 -> xP[t][b][k] fp16
__global__ void cvt_x(const float* __restrict__ x, f16* __restrict__ xP) {
    int P = blockIdx.x * blockDim.x + threadIdx.x;    // pair index
    if (P >= TDIM * BDIM * (KIN / 2)) return;
    int kp = P & 63;
    int b  = (P >> 6) & 63;
    int t  = P >> 12;
    float2 v = ((const float2*)x)[((size_t)b * TDIM + t) * (KIN / 2) + kp];
    f16x2 o = {(f16)v.x, (f16)v.y};
    ((f16x2*)xP)[((size_t)t * BDIM + b) * (KIN / 2) + kp] = o;
}

// ---------------------------------------------------------------------------
__global__ void __launch_bounds__(NTHR, 4) lstm_fused(
    const f16* __restrict__ xP,
    const f16* __restrict__ Wc0, const f16* __restrict__ Wh0,
    const float* __restrict__ bih0, const float* __restrict__ bhh0,
    const f16* __restrict__ Wc1, const f16* __restrict__ Wh1,
    const float* __restrict__ bih1, const float* __restrict__ bhh1,
    f16* ring1, f16* ring2, unsigned* tagA, unsigned* tagB) {

    __shared__ float red[64 * 324 + 16];          // 64 slots (both phases)
    __shared__ __align__(16) f16 hbuf1[32 * 8];   // [b32]*8 + c
    __shared__ __align__(16) f16 hbuf2[32 * 8];

    const int tid  = threadIdx.x;
    const int lane = tid & 63;
    const int w    = __builtin_amdgcn_readfirstlane(tid >> 6);   // 0..15
    const int bid  = (int)blockIdx.x;
    const int cg   = __builtin_amdgcn_readfirstlane(bid & 127);  // col group
    const int bg   = __builtin_amdgcn_readfirstlane(bid >> 7);   // batch group
    const int i0   = cg * 8;        // first owned column
    const int b0   = bg * 32;       // first owned batch

    const int n    = lane & 15;
    const int quad = lane >> 4;
    const int am   = lane & 15;
    const int kq   = quad * 8;

    // weight rows for the two N-tiles
    int wr[2];
    #pragma unroll
    for (int nt = 0; nt < 2; ++nt)
        wr[nt] = i0 + nt * 4 + (n >> 2) + (n & 3) * HDIM;

    // ---- preload stationary weight fragments ([j][nt]) ----
    f16x8 B1x[2];
    f16x8 B1h[2][2], B2i[2][2], B2h[2][2];
    {
        if (w < 4)
            #pragma unroll
            for (int nt = 0; nt < 2; ++nt)
                B1x[nt] = *(const f16x8*)(Wc0 + (size_t)wr[nt] * KIN + w * 32 + kq);
        #pragma unroll
        for (int j = 0; j < 2; ++j) {
            const int ks = (2 * w + j) * 32 + kq;
            #pragma unroll
            for (int nt = 0; nt < 2; ++nt) {
                B1h[j][nt] = *(const f16x8*)(Wh0 + (size_t)wr[nt] * HDIM + ks);
                B2i[j][nt] = *(const f16x8*)(Wc1 + (size_t)wr[nt] * HDIM + ks);
                B2h[j][nt] = *(const f16x8*)(Wh1 + (size_t)wr[nt] * HDIM + ks);
            }
        }
    }

    // ---- owner decomposition: waves 0-3 own layer1, waves 4-7 own layer2 ----
    const int wOwn = w & 3;
    const int cO   = wOwn * 2 + (lane >> 5);   // owned col within 8
    const int b32O = lane & 31;                // owned batch within group
    const int mtO  = (lane >> 4) & 1;
    const int qmO  = lane & 15;
    const int ntO  = cO >> 2;
    const int cit  = cO & 3;                   // col within N-tile
    float bias[4];
    float cc = 0.f;                            // c1 (waves 0-3) / c2 (waves 4-7)
    if (w < 8) {
        const float* bi = (w < 4) ? bih0 : bih1;
        const float* bh = (w < 4) ? bhh0 : bhh1;
        const int i = i0 + cO;
        #pragma unroll
        for (int g = 0; g < 4; ++g)
            bias[g] = bi[i + g * HDIM] + bh[i + g * HDIM];
    }

    // ---- init: zero own region of h^{(-1)} (frame 1) + tag=1 ----
    if (w == 8) {
        uint2 z = {0u, 0u};
        st_cg8(ring1 + FRAME + bg * SUBF + cg * 256 + lane * 4, z);
        VM_DRAIN();
        if (lane == 0) tag_pub(tagA + bid, 1u);
    }
    if (w == 9) {
        uint2 z = {0u, 0u};
        st_cg8(ring2 + FRAME + bg * SUBF + cg * 256 + lane * 4, z);
        VM_DRAIN();
        if (lane == 0) tag_pub(tagB + bid, 1u);
    }

    for (int s = 0; s <= TDIM; ++s) {
        const f16* r1p = ring1 + (size_t)((s + 1) & 1) * FRAME + bg * SUBF; // h1^(s-1)
        const f16* r2p = ring2 + (size_t)(s & 1) * FRAME + bg * SUBF;       // h2^(s-2)

        // ---- concurrent polls (same-bg 128-tag segments) ----
        if (w == 0)  tag_poll128(tagA + bg * 128, lane, (unsigned)(s + 1));
        if (w == 15) tag_poll128(tagB + bg * 128, lane, (unsigned)s);
        __syncthreads();   // S1 (also protects red/hbuf reuse)

        // ---- ALL loads together: A1, A2 (4 dwordx4 each), x (w<4) ----
        f16x8 A1[2][2], A2[2][2];
        #pragma unroll
        for (int j = 0; j < 2; ++j) {
            const int oct = (2 * w + j) * 4 + quad;
            #pragma unroll
            for (int mt = 0; mt < 2; ++mt) {
                A1[j][mt] = ld_cg(r1p + oct * 256 + (mt * 16 + am) * 8);
                A2[j][mt] = ld_cg(r2p + oct * 256 + (mt * 16 + am) * 8);
            }
        }
        f16x8 ax[2];
        if (w < 4) {
            const int ts = (s < TDIM) ? s : (TDIM - 1);
            const f16* xb = xP + (size_t)ts * BDIM * KIN;
            #pragma unroll
            for (int mt = 0; mt < 2; ++mt)
                ax[mt] = *(const f16x8*)(xb + (size_t)(b0 + mt * 16 + am) * KIN + w * 32 + kq);
        }
        VM_WAIT_ALL();

        // ---- all MFMAs: acc = W_hh0 h1 + W_ih0 x ; acc2 = W_ih1 h1 + W_hh1 h2 ----
        f32x4 acc[2][2], acc2[2][2];
        #pragma unroll
        for (int mt = 0; mt < 2; ++mt)
            #pragma unroll
            for (int nt = 0; nt < 2; ++nt) {
                acc[mt][nt]  = (f32x4){0.f, 0.f, 0.f, 0.f};
                acc2[mt][nt] = (f32x4){0.f, 0.f, 0.f, 0.f};
            }
        #pragma unroll
        for (int j = 0; j < 2; ++j)
            #pragma unroll
            for (int nt = 0; nt < 2; ++nt)
                #pragma unroll
                for (int mt = 0; mt < 2; ++mt) {
                    acc[mt][nt]  = MFMA16(A1[j][mt], B1h[j][nt], acc[mt][nt]);
                    acc2[mt][nt] = MFMA16(A1[j][mt], B2i[j][nt], acc2[mt][nt]);
                    acc2[mt][nt] = MFMA16(A2[j][mt], B2h[j][nt], acc2[mt][nt]);
                }
        if (w < 4)
            #pragma unroll
            for (int nt = 0; nt < 2; ++nt)
                #pragma unroll
                for (int mt = 0; mt < 2; ++mt)
                    acc[mt][nt] = MFMA16(ax[mt], B1x[nt], acc[mt][nt]);

        // ---- single fold pass: 64 slots = p*8 + phase*4 + mt*2 + nt ----
        const int p = w & 7;
        if (w < 8) {
            #pragma unroll
            for (int mt = 0; mt < 2; ++mt)
                #pragma unroll
                for (int nt = 0; nt < 2; ++nt) {
                    *(f32x4*)&red[(p * 8 + mt * 2 + nt) * 324 + n * 20 + quad * 4] = acc[mt][nt];
                    *(f32x4*)&red[(p * 8 + 4 + mt * 2 + nt) * 324 + n * 20 + quad * 4] = acc2[mt][nt];
                }
        }
        __syncthreads();   // S2
        if (w >= 8) {
            #pragma unroll
            for (int mt = 0; mt < 2; ++mt)
                #pragma unroll
                for (int nt = 0; nt < 2; ++nt) {
                    float* a1 = &red[(p * 8 + mt * 2 + nt) * 324 + n * 20 + quad * 4];
                    float* a2 = &red[(p * 8 + 4 + mt * 2 + nt) * 324 + n * 20 + quad * 4];
                    f32x4 v1 = *(f32x4*)a1;
                    f32x4 v2 = *(f32x4*)a2;
                    *(f32x4*)a1 = v1 + acc[mt][nt];
                    *(f32x4*)a2 = v2 + acc2[mt][nt];
                }
        }
        __syncthreads();   // S3

        // ---- PARALLEL owner reduces ----
        if (w < 4 && s < TDIM) {           // layer 1 -> h1^(s)
            float g4[4];
            #pragma unroll
            for (int g = 0; g < 4; ++g) {
                float sum = bias[g];
                #pragma unroll
                for (int pp = 0; pp < 8; ++pp)
                    sum += red[(pp * 8 + mtO * 2 + ntO) * 324 + (cit * 4 + g) * 20 + qmO];
                g4[g] = sum;
            }
            float ig = sigm(g4[0]), fg = sigm(g4[1]);
            float gg = tanhf(g4[2]), og = sigm(g4[3]);
            cc = fg * cc + ig * gg;
            hbuf1[b32O * 8 + cO] = (f16)(og * tanhf(cc));
        }
        if (w >= 4 && w < 8 && s >= 1) {   // layer 2 -> h2^(s-1)
            float g4[4];
            #pragma unroll
            for (int g = 0; g < 4; ++g) {
                float sum = bias[g];
                #pragma unroll
                for (int pp = 0; pp < 8; ++pp)
                    sum += red[(pp * 8 + 4 + mtO * 2 + ntO) * 324 + (cit * 4 + g) * 20 + qmO];
                g4[g] = sum;
            }
            float ig = sigm(g4[0]), fg = sigm(g4[1]);
            float gg = tanhf(g4[2]), og = sigm(g4[3]);
            cc = fg * cc + ig * gg;
            hbuf2[b32O * 8 + cO] = (f16)(og * tanhf(cc));
        }
        __syncthreads();   // S4: hbufs ready

        // ---- PARALLEL publishes ----
        if (w == 8 && s < TDIM) {
            uint2 v = *(const uint2*)&hbuf1[lane * 4];
            st_cg8(ring1 + (size_t)(s & 1) * FRAME + bg * SUBF + cg * 256 + lane * 4, v);
            VM_DRAIN();
            if (lane == 0) tag_pub(tagA + bid, (unsigned)(s + 2));
        }
        if (w == 9 && s >= 1) {
            uint2 v = *(const uint2*)&hbuf2[lane * 4];
            st_cg8(ring2 + (size_t)((s + 1) & 1) * FRAME + bg * SUBF + cg * 256 + lane * 4, v);
            VM_DRAIN();
            if (lane == 0) tag_pub(tagB + bid, (unsigned)(s + 1));
        }
    }
    // final h2^{(511)} is in ring2 frame 1
}

// ---------------------------------------------------------------------------
// out[b] = dot(h2[b, :], fc_w) + fc_b.  h2 in subframe/octet layout:
//   idx(k, b) = (b>>5)*SUBF + (k>>3)*256 + (b&31)*8 + (k&7)
// ---------------------------------------------------------------------------
__global__ void fc_kernel(const f16* __restrict__ h2f,
                          const float* __restrict__ fcw,
                          const float* __restrict__ fcb,
                          float* __restrict__ out) {
    __shared__ float red[256];
    const int tid = threadIdx.x;
    const int b = tid >> 2, q = tid & 3;
    const int base = (b >> 5) * SUBF + (b & 31) * 8;
    float s = 0.f;
    for (int oct = q * 32; oct < (q + 1) * 32; ++oct) {
        f16x8 v = *(const f16x8*)(h2f + base + oct * 256);
        #pragma unroll
        for (int j = 0; j < 8; ++j)
            s = fmaf((float)v[j], fcw[oct * 8 + j], s);
    }
    red[tid] = s;
    __syncthreads();
    if (q == 0)
        out[b] = red[tid] + red[tid + 1] + red[tid + 2] + red[tid + 3] + fcb[0];
}

// ---------------------------------------------------------------------------
extern "C" void kernel_launch(void* const* d_in, const int* in_sizes, int n_in,
                              void* d_out, int out_size, void* d_ws, size_t ws_size,
                              hipStream_t stream) {
    const float* x    = (const float*)d_in[0];
    const float* Wih0 = (const float*)d_in[1];
    const float* Whh0 = (const float*)d_in[2];
    const float* bih0 = (const float*)d_in[3];
    const float* bhh0 = (const float*)d_in[4];
    const float* Wih1 = (const float*)d_in[5];
    const float* Whh1 = (const float*)d_in[6];
    const float* bih1 = (const float*)d_in[7];
    const float* bhh1 = (const float*)d_in[8];
    const float* fcw  = (const float*)d_in[9];
    const float* fcb  = (const float*)d_in[10];
    float* out = (float*)d_out;

    // workspace (halfs): xP | Wc0 | Wh0 | Wc1 | Wh1 | ring1 | ring2 | tags
    f16* xPd   = (f16*)d_ws;
    f16* Wc0   = xPd + (size_t)TDIM * BDIM * KIN;
    f16* Wh0   = Wc0 + (size_t)4 * HDIM * KIN;
    f16* Wc1   = Wh0 + (size_t)4 * HDIM * HDIM;
    f16* Wh1   = Wc1 + (size_t)4 * HDIM * HDIM;
    f16* ring1 = Wh1 + (size_t)4 * HDIM * HDIM;
    f16* ring2 = ring1 + 2 * FRAME;
    unsigned* tagA = (unsigned*)(ring2 + 2 * FRAME);
    unsigned* tagB = tagA + 512;      // 2 KB apart

    hipMemsetAsync(tagA, 0, 4096, stream);
    {
        int n2 = 4 * HDIM * KIN / 2;
        cvt_w<<<dim3((n2 + 255) / 256), dim3(256), 0, stream>>>(Wih0, Wc0, n2);
        n2 = 4 * HDIM * HDIM / 2;
        cvt_w<<<dim3((n2 + 255) / 256), dim3(256), 0, stream>>>(Whh0, Wh0, n2);
        cvt_w<<<dim3((n2 + 255) / 256), dim3(256), 0, stream>>>(Whh1, Wh1, n2);
        cvt_w<<<dim3((n2 + 255) / 256), dim3(256), 0, stream>>>(Wih1, Wc1, n2);
    }
    {
        int np = TDIM * BDIM * (KIN / 2);
        cvt_x<<<dim3((np + 255) / 256), dim3(256), 0, stream>>>(x, xPd);
    }

    void* args[13];
    args[0]  = (void*)&xPd;
    args[1]  = (void*)&Wc0;
    args[2]  = (void*)&Wh0;
    args[3]  = (void*)&bih0;
    args[4]  = (void*)&bhh0;
    args[5]  = (void*)&Wc1;
    args[6]  = (void*)&Wh1;
    args[7]  = (void*)&bih1;
    args[8]  = (void*)&bhh1;
    args[9]  = (void*)&ring1;
    args[10] = (void*)&ring2;
    args[11] = (void*)&tagA;
    args[12] = (void*)&tagB;
    hipLaunchCooperativeKernel(reinterpret_cast<void*>(lstm_fused), dim3(NBLK), dim3(NTHR),
                               args, 0, stream);

    fc_kernel<<<dim3(1), dim3(256), 0, stream>>>(ring2 + FRAME, fcw, fcb, out);
}

// Round 8
// 6728.905 us; speedup vs baseline: 1.0020x; 1.0020x over previous
//
#include <hip/hip_runtime.h>
#include <math.h>

#define HDIM 1024
#define BDIM 64
#define TDIM 512
#define KIN  128
#define NBLK 256
#define NTHR 1024           // 16 waves
#define FRAME (HDIM * BDIM) // halfs per ring frame (2-deep rings)
#define SUBF  (HDIM * 32)   // halfs per 32-batch subframe

typedef _Float16 f16;
typedef __attribute__((ext_vector_type(2))) _Float16 f16x2;
typedef __attribute__((ext_vector_type(8))) _Float16 f16x8;
typedef __attribute__((ext_vector_type(4))) float f32x4;
typedef __attribute__((ext_vector_type(2))) unsigned u32x2;
typedef __attribute__((ext_vector_type(4))) unsigned u32x4;

#define MFMA16(a, b, c) __builtin_amdgcn_mfma_f32_16x16x32_f16((a), (b), (c), 0, 0, 0)

__device__ __forceinline__ float sigm(float x) { return 1.0f / (1.0f + expf(-x)); }

// ---------------------------------------------------------------------------
// r15 = r14 merged single-stage body + REGISTER-CAP FIX.
// r14 post-mortem: FETCH_SIZE 579MB -> 1.85GB with WRITE +24MB only =
// loop-invariant spill reloads (stored once, reloaded 513x). VGPR_Count
// pinned at 64 because __launch_bounds__(1024, 4) is honored as 4 co-resident
// blocks -> 8 waves/SIMD target -> cap 512/8 = 64 VGPR. The merged body needs
// ~110 co-live VGPRs -> everything above 64 spilled to scratch inside the
// hot loop. Grid = 256 blocks = 1 block/CU (grid-limited), so declare
// __launch_bounds__(1024, 1): launchability bound for a 16-wave block is
// VGPR <= 512/4 = 128 -> compiler allocates up to 128, no spills.
// Structure (verified correct in r14): concurrent polls -> 1 barrier -> ALL
// loads (A1+A2+x, one vmcnt(0)) -> all MFMAs -> one 64-slot fold (2 barriers)
// -> PARALLEL owner reduces (waves 0-3: h1, waves 4-7: h2) -> 1 barrier ->
// PARALLEL publishes (wave8: ring1+tagA, wave9: ring2+tagB).
// Subframe layout (halfs): idx(k, b32) = (k>>3)*256 + b32*8 + (k&7).
// All ring I/O sc0sc1 (L3 coherence point; r11 cached+inv was 6x worse).
// Step semantics: at step s compute h1^(s) (from h1^(s-1), x_s) and h2^(s-1)
// (from h1^(s-1), h2^(s-2)).
//   top of s: tagA >= s+1 (h1^(s-1)), tagB >= s (h2^(s-2)).
//   publish h1^(s) -> tagA=s+2; publish h2^(s-1) -> tagB=s+1.
// ---------------------------------------------------------------------------
__device__ __forceinline__ f16x8 ld_cg(const f16* p) {
    f16x8 r;
    asm volatile("global_load_dwordx4 %0, %1, off sc0 sc1"
                 : "=v"(r) : "v"(p) : "memory");
    return r;
}
__device__ __forceinline__ void st_cg8(f16* p, uint2 v) {
    asm volatile("global_store_dwordx2 %0, %1, off sc0 sc1"
                 :: "v"(p), "v"(v) : "memory");
}
#define VM_DRAIN() asm volatile("s_waitcnt vmcnt(0)" ::: "memory")
// all VMEM done + no MFMA hoisting above the wait (guide rule #18)
#define VM_WAIT_ALL()                                                    \
    do {                                                                 \
        asm volatile("s_waitcnt vmcnt(0)" ::: "memory");                 \
        __builtin_amdgcn_sched_barrier(0);                               \
    } while (0)

__device__ __forceinline__ void tag_pub(unsigned* tag, unsigned v) {
    asm volatile("global_store_dword %0, %1, off sc0 sc1"
                 :: "v"(tag), "v"(v) : "memory");
}
// poll 128 contiguous tags (one bg stream): 64 lanes x dwordx2
__device__ __forceinline__ void tag_poll128(const unsigned* tags, int lane,
                                            unsigned tgt) {
    const unsigned* p = tags + lane * 2;
    for (;;) {
        u32x2 t;
        asm volatile("global_load_dwordx2 %0, %1, off sc0 sc1\n\t"
                     "s_waitcnt vmcnt(0)"
                     : "=v"(t) : "v"(p) : "memory");
        bool ok = (t.x >= tgt) && (t.y >= tgt);
        if (__all(ok)) break;
        __builtin_amdgcn_s_sleep(1);
    }
}

// ---------------------------------------------------------------------------
__global__ void cvt_w(const float* __restrict__ src, f16* __restrict__ dst, int n2) {
    int i = blockIdx.x * blockDim.x + threadIdx.x;
    if (i < n2) {
        float2 a = ((const float2*)src)[i];
        f16x2 o = {(f16)a.x, (f16)a.y};
        ((f16x2*)dst)[i] = o;
    }
}

// x[b][t][k] fp32 -> xP[t][b][k] fp16
__global__ void cvt_x(const float* __restrict__ x, f16* __restrict__ xP) {
    int P = blockIdx.x * blockDim.x + threadIdx.x;    // pair index
    if (P >= TDIM * BDIM * (KIN / 2)) return;
    int kp = P & 63;
    int b  = (P >> 6) & 63;
    int t  = P >> 12;
    float2 v = ((const float2*)x)[((size_t)b * TDIM + t) * (KIN / 2) + kp];
    f16x2 o = {(f16)v.x, (f16)v.y};
    ((f16x2*)xP)[((size_t)t * BDIM + b) * (KIN / 2) + kp] = o;
}

// ---------------------------------------------------------------------------
__global__ void __launch_bounds__(NTHR, 1) lstm_fused(
    const f16* __restrict__ xP,
    const f16* __restrict__ Wc0, const f16* __restrict__ Wh0,
    const float* __restrict__ bih0, const float* __restrict__ bhh0,
    const f16* __restrict__ Wc1, const f16* __restrict__ Wh1,
    const float* __restrict__ bih1, const float* __restrict__ bhh1,
    f16* ring1, f16* ring2, unsigned* tagA, unsigned* tagB) {

    __shared__ float red[64 * 324 + 16];          // 64 slots (both phases)
    __shared__ __align__(16) f16 hbuf1[32 * 8];   // [b32]*8 + c
    __shared__ __align__(16) f16 hbuf2[32 * 8];

    const int tid  = threadIdx.x;
    const int lane = tid & 63;
    const int w    = __builtin_amdgcn_readfirstlane(tid >> 6);   // 0..15
    const int bid  = (int)blockIdx.x;
    const int cg   = __builtin_amdgcn_readfirstlane(bid & 127);  // col group
    const int bg   = __builtin_amdgcn_readfirstlane(bid >> 7);   // batch group
    const int i0   = cg * 8;        // first owned column
    const int b0   = bg * 32;       // first owned batch

    const int n    = lane & 15;
    const int quad = lane >> 4;
    const int am   = lane & 15;
    const int kq   = quad * 8;

    // weight rows for the two N-tiles
    int wr[2];
    #pragma unroll
    for (int nt = 0; nt < 2; ++nt)
        wr[nt] = i0 + nt * 4 + (n >> 2) + (n & 3) * HDIM;

    // ---- preload stationary weight fragments ([j][nt]) ----
    f16x8 B1x[2];
    f16x8 B1h[2][2], B2i[2][2], B2h[2][2];
    {
        if (w < 4)
            #pragma unroll
            for (int nt = 0; nt < 2; ++nt)
                B1x[nt] = *(const f16x8*)(Wc0 + (size_t)wr[nt] * KIN + w * 32 + kq);
        #pragma unroll
        for (int j = 0; j < 2; ++j) {
            const int ks = (2 * w + j) * 32 + kq;
            #pragma unroll
            for (int nt = 0; nt < 2; ++nt) {
                B1h[j][nt] = *(const f16x8*)(Wh0 + (size_t)wr[nt] * HDIM + ks);
                B2i[j][nt] = *(const f16x8*)(Wc1 + (size_t)wr[nt] * HDIM + ks);
                B2h[j][nt] = *(const f16x8*)(Wh1 + (size_t)wr[nt] * HDIM + ks);
            }
        }
    }

    // ---- owner decomposition: waves 0-3 own layer1, waves 4-7 own layer2 ----
    const int wOwn = w & 3;
    const int cO   = wOwn * 2 + (lane >> 5);   // owned col within 8
    const int b32O = lane & 31;                // owned batch within group
    const int mtO  = (lane >> 4) & 1;
    const int qmO  = lane & 15;
    const int ntO  = cO >> 2;
    const int cit  = cO & 3;                   // col within N-tile
    float bias[4];
    float cc = 0.f;                            // c1 (waves 0-3) / c2 (waves 4-7)
    if (w < 8) {
        const float* bi = (w < 4) ? bih0 : bih1;
        const float* bh = (w < 4) ? bhh0 : bhh1;
        const int i = i0 + cO;
        #pragma unroll
        for (int g = 0; g < 4; ++g)
            bias[g] = bi[i + g * HDIM] + bh[i + g * HDIM];
    }

    // ---- init: zero own region of h^{(-1)} (frame 1) + tag=1 ----
    if (w == 8) {
        uint2 z = {0u, 0u};
        st_cg8(ring1 + FRAME + bg * SUBF + cg * 256 + lane * 4, z);
        VM_DRAIN();
        if (lane == 0) tag_pub(tagA + bid, 1u);
    }
    if (w == 9) {
        uint2 z = {0u, 0u};
        st_cg8(ring2 + FRAME + bg * SUBF + cg * 256 + lane * 4, z);
        VM_DRAIN();
        if (lane == 0) tag_pub(tagB + bid, 1u);
    }

    for (int s = 0; s <= TDIM; ++s) {
        const f16* r1p = ring1 + (size_t)((s + 1) & 1) * FRAME + bg * SUBF; // h1^(s-1)
        const f16* r2p = ring2 + (size_t)(s & 1) * FRAME + bg * SUBF;       // h2^(s-2)

        // ---- concurrent polls (same-bg 128-tag segments) ----
        if (w == 0)  tag_poll128(tagA + bg * 128, lane, (unsigned)(s + 1));
        if (w == 15) tag_poll128(tagB + bg * 128, lane, (unsigned)s);
        __syncthreads();   // S1 (also protects red/hbuf reuse)

        // ---- ALL loads together: A1, A2 (4 dwordx4 each), x (w<4) ----
        f16x8 A1[2][2], A2[2][2];
        #pragma unroll
        for (int j = 0; j < 2; ++j) {
            const int oct = (2 * w + j) * 4 + quad;
            #pragma unroll
            for (int mt = 0; mt < 2; ++mt) {
                A1[j][mt] = ld_cg(r1p + oct * 256 + (mt * 16 + am) * 8);
                A2[j][mt] = ld_cg(r2p + oct * 256 + (mt * 16 + am) * 8);
            }
        }
        f16x8 ax[2];
        if (w < 4) {
            const int ts = (s < TDIM) ? s : (TDIM - 1);
            const f16* xb = xP + (size_t)ts * BDIM * KIN;
            #pragma unroll
            for (int mt = 0; mt < 2; ++mt)
                ax[mt] = *(const f16x8*)(xb + (size_t)(b0 + mt * 16 + am) * KIN + w * 32 + kq);
        }
        VM_WAIT_ALL();

        // ---- all MFMAs: acc = W_hh0 h1 + W_ih0 x ; acc2 = W_ih1 h1 + W_hh1 h2 ----
        f32x4 acc[2][2], acc2[2][2];
        #pragma unroll
        for (int mt = 0; mt < 2; ++mt)
            #pragma unroll
            for (int nt = 0; nt < 2; ++nt) {
                acc[mt][nt]  = (f32x4){0.f, 0.f, 0.f, 0.f};
                acc2[mt][nt] = (f32x4){0.f, 0.f, 0.f, 0.f};
            }
        #pragma unroll
        for (int j = 0; j < 2; ++j)
            #pragma unroll
            for (int nt = 0; nt < 2; ++nt)
                #pragma unroll
                for (int mt = 0; mt < 2; ++mt) {
                    acc[mt][nt]  = MFMA16(A1[j][mt], B1h[j][nt], acc[mt][nt]);
                    acc2[mt][nt] = MFMA16(A1[j][mt], B2i[j][nt], acc2[mt][nt]);
                    acc2[mt][nt] = MFMA16(A2[j][mt], B2h[j][nt], acc2[mt][nt]);
                }
        if (w < 4)
            #pragma unroll
            for (int nt = 0; nt < 2; ++nt)
                #pragma unroll
                for (int mt = 0; mt < 2; ++mt)
                    acc[mt][nt] = MFMA16(ax[mt], B1x[nt], acc[mt][nt]);

        // ---- single fold pass: 64 slots = p*8 + phase*4 + mt*2 + nt ----
        const int p = w & 7;
        if (w < 8) {
            #pragma unroll
            for (int mt = 0; mt < 2; ++mt)
                #pragma unroll
                for (int nt = 0; nt < 2; ++nt) {
                    *(f32x4*)&red[(p * 8 + mt * 2 + nt) * 324 + n * 20 + quad * 4] = acc[mt][nt];
                    *(f32x4*)&red[(p * 8 + 4 + mt * 2 + nt) * 324 + n * 20 + quad * 4] = acc2[mt][nt];
                }
        }
        __syncthreads();   // S2
        if (w >= 8) {
            #pragma unroll
            for (int mt = 0; mt < 2; ++mt)
                #pragma unroll
                for (int nt = 0; nt < 2; ++nt) {
                    float* a1 = &red[(p * 8 + mt * 2 + nt) * 324 + n * 20 + quad * 4];
                    float* a2 = &red[(p * 8 + 4 + mt * 2 + nt) * 324 + n * 20 + quad * 4];
                    f32x4 v1 = *(f32x4*)a1;
                    f32x4 v2 = *(f32x4*)a2;
                    *(f32x4*)a1 = v1 + acc[mt][nt];
                    *(f32x4*)a2 = v2 + acc2[mt][nt];
                }
        }
        __syncthreads();   // S3

        // ---- PARALLEL owner reduces ----
        if (w < 4 && s < TDIM) {           // layer 1 -> h1^(s)
            float g4[4];
            #pragma unroll
            for (int g = 0; g < 4; ++g) {
                float sum = bias[g];
                #pragma unroll
                for (int pp = 0; pp < 8; ++pp)
                    sum += red[(pp * 8 + mtO * 2 + ntO) * 324 + (cit * 4 + g) * 20 + qmO];
                g4[g] = sum;
            }
            float ig = sigm(g4[0]), fg = sigm(g4[1]);
            float gg = tanhf(g4[2]), og = sigm(g4[3]);
            cc = fg * cc + ig * gg;
            hbuf1[b32O * 8 + cO] = (f16)(og * tanhf(cc));
        }
        if (w >= 4 && w < 8 && s >= 1) {   // layer 2 -> h2^(s-1)
            float g4[4];
            #pragma unroll
            for (int g = 0; g < 4; ++g) {
                float sum = bias[g];
                #pragma unroll
                for (int pp = 0; pp < 8; ++pp)
                    sum += red[(pp * 8 + 4 + mtO * 2 + ntO) * 324 + (cit * 4 + g) * 20 + qmO];
                g4[g] = sum;
            }
            float ig = sigm(g4[0]), fg = sigm(g4[1]);
            float gg = tanhf(g4[2]), og = sigm(g4[3]);
            cc = fg * cc + ig * gg;
            hbuf2[b32O * 8 + cO] = (f16)(og * tanhf(cc));
        }
        __syncthreads();   // S4: hbufs ready

        // ---- PARALLEL publishes ----
        if (w == 8 && s < TDIM) {
            uint2 v = *(const uint2*)&hbuf1[lane * 4];
            st_cg8(ring1 + (size_t)(s & 1) * FRAME + bg * SUBF + cg * 256 + lane * 4, v);
            VM_DRAIN();
            if (lane == 0) tag_pub(tagA + bid, (unsigned)(s + 2));
        }
        if (w == 9 && s >= 1) {
            uint2 v = *(const uint2*)&hbuf2[lane * 4];
            st_cg8(ring2 + (size_t)((s + 1) & 1) * FRAME + bg * SUBF + cg * 256 + lane * 4, v);
            VM_DRAIN();
            if (lane == 0) tag_pub(tagB + bid, (unsigned)(s + 1));
        }
    }
    // final h2^{(511)} is in ring2 frame 1
}

// ---------------------------------------------------------------------------
// out[b] = dot(h2[b, :], fc_w) + fc_b.  h2 in subframe/octet layout:
//   idx(k, b) = (b>>5)*SUBF + (k>>3)*256 + (b&31)*8 + (k&7)
// ---------------------------------------------------------------------------
__global__ void fc_kernel(const f16* __restrict__ h2f,
                          const float* __restrict__ fcw,
                          const float* __restrict__ fcb,
                          float* __restrict__ out) {
    __shared__ float red[256];
    const int tid = threadIdx.x;
    const int b = tid >> 2, q = tid & 3;
    const int base = (b >> 5) * SUBF + (b & 31) * 8;
    float s = 0.f;
    for (int oct = q * 32; oct < (q + 1) * 32; ++oct) {
        f16x8 v = *(const f16x8*)(h2f + base + oct * 256);
        #pragma unroll
        for (int j = 0; j < 8; ++j)
            s = fmaf((float)v[j], fcw[oct * 8 + j], s);
    }
    red[tid] = s;
    __syncthreads();
    if (q == 0)
        out[b] = red[tid] + red[tid + 1] + red[tid + 2] + red[tid + 3] + fcb[0];
}

// ---------------------------------------------------------------------------
extern "C" void kernel_launch(void* const* d_in, const int* in_sizes, int n_in,
                              void* d_out, int out_size, void* d_ws, size_t ws_size,
                              hipStream_t stream) {
    const float* x    = (const float*)d_in[0];
    const float* Wih0 = (const float*)d_in[1];
    const float* Whh0 = (const float*)d_in[2];
    const float* bih0 = (const float*)d_in[3];
    const float* bhh0 = (const float*)d_in[4];
    const float* Wih1 = (const float*)d_in[5];
    const float* Whh1 = (const float*)d_in[6];
    const float* bih1 = (const float*)d_in[7];
    const float* bhh1 = (const float*)d_in[8];
    const float* fcw  = (const float*)d_in[9];
    const float* fcb  = (const float*)d_in[10];
    float* out = (float*)d_out;

    // workspace (halfs): xP | Wc0 | Wh0 | Wc1 | Wh1 | ring1 | ring2 | tags
    f16* xPd   = (f16*)d_ws;
    f16* Wc0   = xPd + (size_t)TDIM * BDIM * KIN;
    f16* Wh0   = Wc0 + (size_t)4 * HDIM * KIN;
    f16* Wc1   = Wh0 + (size_t)4 * HDIM * HDIM;
    f16* Wh1   = Wc1 + (size_t)4 * HDIM * HDIM;
    f16* ring1 = Wh1 + (size_t)4 * HDIM * HDIM;
    f16* ring2 = ring1 + 2 * FRAME;
    unsigned* tagA = (unsigned*)(ring2 + 2 * FRAME);
    unsigned* tagB = tagA + 512;      // 2 KB apart

    hipMemsetAsync(tagA, 0, 4096, stream);
    {
        int n2 = 4 * HDIM * KIN / 2;
        cvt_w<<<dim3((n2 + 255) / 256), dim3(256), 0, stream>>>(Wih0, Wc0, n2);
        n2 = 4 * HDIM * HDIM / 2;
        cvt_w<<<dim3((n2 + 255) / 256), dim3(256), 0, stream>>>(Whh0, Wh0, n2);
        cvt_w<<<dim3((n2 + 255) / 256), dim3(256), 0, stream>>>(Whh1, Wh1, n2);
        cvt_w<<<dim3((n2 + 255) / 256), dim3(256), 0, stream>>>(Wih1, Wc1, n2);
    }
    {
        int np = TDIM * BDIM * (KIN / 2);
        cvt_x<<<dim3((np + 255) / 256), dim3(256), 0, stream>>>(x, xPd);
    }

    void* args[13];
    args[0]  = (void*)&xPd;
    args[1]  = (void*)&Wc0;
    args[2]  = (void*)&Wh0;
    args[3]  = (void*)&bih0;
    args[4]  = (void*)&bhh0;
    args[5]  = (void*)&Wc1;
    args[6]  = (void*)&Wh1;
    args[7]  = (void*)&bih1;
    args[8]  = (void*)&bhh1;
    args[9]  = (void*)&ring1;
    args[10] = (void*)&ring2;
    args[11] = (void*)&tagA;
    args[12] = (void*)&tagB;
    hipLaunchCooperativeKernel(reinterpret_cast<void*>(lstm_fused), dim3(NBLK), dim3(NTHR),
                               args, 0, stream);

    fc_kernel<<<dim3(1), dim3(256), 0, stream>>>(ring2 + FRAME, fcw, fcb, out);
}

// Round 9
// 6475.213 us; speedup vs baseline: 1.0412x; 1.0392x over previous
//
#include <hip/hip_runtime.h>
#include <math.h>

#define HDIM 1024
#define BDIM 64
#define TDIM 512
#define KIN  128
#define NBLK 256
#define NTHR 1024           // 16 waves
#define FRAME (HDIM * BDIM) // halfs per ring frame (2-deep rings)
#define SUBF  (HDIM * 32)   // halfs per 32-batch subframe

typedef _Float16 f16;
typedef __attribute__((ext_vector_type(2))) _Float16 f16x2;
typedef __attribute__((ext_vector_type(8))) _Float16 f16x8;
typedef __attribute__((ext_vector_type(4))) float f32x4;
typedef __attribute__((ext_vector_type(2))) unsigned u32x2;
typedef __attribute__((ext_vector_type(4))) unsigned u32x4;

#define MFMA16(a, b, c) __builtin_amdgcn_mfma_f32_16x16x32_f16((a), (b), (c), 0, 0, 0)

__device__ __forceinline__ float sigm(float x) { return 1.0f / (1.0f + expf(-x)); }

// ---------------------------------------------------------------------------
// r16 = r12 (verified 3087us, two staggered phases) + two chain cuts:
//  (1) single-pass 64-slot fold: all 16 waves WRITE partials (slot = w*4+tile);
//      owners read 16 partials directly. Removes S3/S6 add-passes (7->5
//      barriers/step).
//  (2) wave-8 publish overlap: store h1 -> issue A2 loads -> vmcnt(4) (waits
//      only the oldest = the store; vmcnt retires in issue order) -> tagA.
//      The publish drain overlaps wave 8's A2 loads instead of serializing.
// Post-mortems encoded: r14/r15 showed FETCH explosion = poll-spin traffic
// (symptom of wait time); moving tagB poll to top-of-step kills the stagger
// that hides the ~2us publish->poll RTT. Stagger is preserved here:
//   h1 chain: publish mid-body(s) -> poll top(s+1);
//   h2 chain: publish end(s-1) -> poll mid-body(s) (wave 15, during reduce1).
// Tiling (r12): 256 blocks = 128 cg x 2 bg; block owns 8 cols x 32 batches;
// 16-way K-split. Subframe layout: idx(k,b32) = (k>>3)*256 + b32*8 + (k&7).
// All ring I/O sc0sc1 (L3 coherence point; r11 cached+inv was 6x worse).
// Step s: compute h1^(s) (needs tagA>=s+1) and h2^(s-1) (needs tagB>=s).
// Publish h1^(s) -> tagA=s+2 (mid-body); h2^(s-1) -> tagB=s+1 (end).
// ---------------------------------------------------------------------------
__device__ __forceinline__ f16x8 ld_cg(const f16* p) {
    f16x8 r;
    asm volatile("global_load_dwordx4 %0, %1, off sc0 sc1"
                 : "=v"(r) : "v"(p) : "memory");
    return r;
}
#define VM_WAIT4(r0, r1, r2, r3)                                         \
    asm volatile("s_waitcnt vmcnt(0)"                                    \
                 : "+v"(r0), "+v"(r1), "+v"(r2), "+v"(r3))

__device__ __forceinline__ void st_cg8(f16* p, uint2 v) {
    asm volatile("global_store_dwordx2 %0, %1, off sc0 sc1"
                 :: "v"(p), "v"(v) : "memory");
}
#define VM_DRAIN() asm volatile("s_waitcnt vmcnt(0)" ::: "memory")

__device__ __forceinline__ void tag_pub(unsigned* tag, unsigned v) {
    asm volatile("global_store_dword %0, %1, off sc0 sc1"
                 :: "v"(tag), "v"(v) : "memory");
}
// poll 128 contiguous tags (one bg stream): 64 lanes x dwordx2
__device__ __forceinline__ void tag_poll128(const unsigned* tags, int lane,
                                            unsigned tgt) {
    const unsigned* p = tags + lane * 2;
    for (;;) {
        u32x2 t;
        asm volatile("global_load_dwordx2 %0, %1, off sc0 sc1\n\t"
                     "s_waitcnt vmcnt(0)"
                     : "=v"(t) : "v"(p) : "memory");
        bool ok = (t.x >= tgt) && (t.y >= tgt);
        if (__all(ok)) break;
        __builtin_amdgcn_s_sleep(1);
    }
}

// ---------------------------------------------------------------------------
__global__ void cvt_w(const float* __restrict__ src, f16* __restrict__ dst, int n2) {
    int i = blockIdx.x * blockDim.x + threadIdx.x;
    if (i < n2) {
        float2 a = ((const float2*)src)[i];
        f16x2 o = {(f16)a.x, (f16)a.y};
        ((f16x2*)dst)[i] = o;
    }
}

// x[b][t][k] fp32 -> xP[t][b][k] fp16
__global__ void cvt_x(const float* __restrict__ x, f16* __restrict__ xP) {
    int P = blockIdx.x * blockDim.x + threadIdx.x;    // pair index
    if (P >= TDIM * BDIM * (KIN / 2)) return;
    int kp = P & 63;
    int b  = (P >> 6) & 63;
    int t  = P >> 12;
    float2 v = ((const float2*)x)[((size_t)b * TDIM + t) * (KIN / 2) + kp];
    f16x2 o = {(f16)v.x, (f16)v.y};
    ((f16x2*)xP)[((size_t)t * BDIM + b) * (KIN / 2) + kp] = o;
}

// ---------------------------------------------------------------------------
__global__ void __launch_bounds__(NTHR, 4) lstm_fused(
    const f16* __restrict__ xP,
    const f16* __restrict__ Wc0, const f16* __restrict__ Wh0,
    const float* __restrict__ bih0, const float* __restrict__ bhh0,
    const f16* __restrict__ Wc1, const f16* __restrict__ Wh1,
    const float* __restrict__ bih1, const float* __restrict__ bhh1,
    f16* ring1, f16* ring2, unsigned* tagA, unsigned* tagB) {

    __shared__ float red[64 * 324 + 16];          // 64 slots (16 waves x 4 tiles)
    __shared__ __align__(16) f16 hbuf1[32 * 8];   // [b32]*8 + c
    __shared__ __align__(16) f16 hbuf2[32 * 8];

    const int tid  = threadIdx.x;
    const int lane = tid & 63;
    const int w    = __builtin_amdgcn_readfirstlane(tid >> 6);   // 0..15
    const int bid  = (int)blockIdx.x;
    const int cg   = __builtin_amdgcn_readfirstlane(bid & 127);  // col group
    const int bg   = __builtin_amdgcn_readfirstlane(bid >> 7);   // batch group
    const int i0   = cg * 8;        // first owned column
    const int b0   = bg * 32;       // first owned batch

    const int n    = lane & 15;
    const int quad = lane >> 4;
    const int am   = lane & 15;
    const int kq   = quad * 8;

    // weight rows for the two N-tiles
    int wr[2];
    #pragma unroll
    for (int nt = 0; nt < 2; ++nt)
        wr[nt] = i0 + nt * 4 + (n >> 2) + (n & 3) * HDIM;

    // ---- preload stationary weight fragments ([j][nt]) ----
    f16x8 B1x[2];
    f16x8 B1h[2][2], B2i[2][2], B2h[2][2];
    {
        if (w < 4)
            #pragma unroll
            for (int nt = 0; nt < 2; ++nt)
                B1x[nt] = *(const f16x8*)(Wc0 + (size_t)wr[nt] * KIN + w * 32 + kq);
        #pragma unroll
        for (int j = 0; j < 2; ++j) {
            const int ks = (2 * w + j) * 32 + kq;
            #pragma unroll
            for (int nt = 0; nt < 2; ++nt) {
                B1h[j][nt] = *(const f16x8*)(Wh0 + (size_t)wr[nt] * HDIM + ks);
                B2i[j][nt] = *(const f16x8*)(Wc1 + (size_t)wr[nt] * HDIM + ks);
                B2h[j][nt] = *(const f16x8*)(Wh1 + (size_t)wr[nt] * HDIM + ks);
            }
        }
    }

    // ---- owner state (waves 0..3): lane -> (c = w*2 + lane>>5, b32 = lane&31)
    float bias1[4], bias2[4];
    float c1 = 0.f, c2 = 0.f;
    const int il   = w & 3;
    const int cO   = il * 2 + (lane >> 5);     // owned col within 8
    const int b32O = lane & 31;                // owned batch within group
    const int mtO  = (lane >> 4) & 1;
    const int qmO  = lane & 15;
    const int ntO  = cO >> 2;
    const int nbO  = (cO & 3) * 4;             // row base within tile = cit*4
    if (w < 4) {
        const int i = i0 + cO;
        #pragma unroll
        for (int g = 0; g < 4; ++g) {
            bias1[g] = bih0[i + g * HDIM] + bhh0[i + g * HDIM];
            bias2[g] = bih1[i + g * HDIM] + bhh1[i + g * HDIM];
        }
    }

    // ---- init: zero own region of h^{(-1)} (frame 1) + tag=1 ----
    if (w == 8) {
        uint2 z = {0u, 0u};
        st_cg8(ring1 + FRAME + bg * SUBF + cg * 256 + lane * 4, z);
        VM_DRAIN();
        if (lane == 0) tag_pub(tagA + bid, 1u);
    }
    if (w == 9) {
        uint2 z = {0u, 0u};
        st_cg8(ring2 + FRAME + bg * SUBF + cg * 256 + lane * 4, z);
        VM_DRAIN();
        if (lane == 0) tag_pub(tagB + bid, 1u);
    }

    for (int s = 0; s <= TDIM; ++s) {
        const f16* r1p = ring1 + (size_t)((s + 1) & 1) * FRAME + bg * SUBF; // h1^(s-1)
        const f16* r2p = ring2 + (size_t)(s & 1) * FRAME + bg * SUBF;       // h2^(s-2)

        // ---- wait for h1^(s-1): wave 0 polls its bg's 128 tags ----
        if (w == 0) tag_poll128(tagA + bg * 128, lane, (unsigned)(s + 1));
        __syncthreads();   // S1 (also protects red/hbuf reuse from prev iter)

        // ---- A1 fragments: [j][mt], one dwordx4 each (4 loads/wave) ----
        f16x8 A1[2][2];
        #pragma unroll
        for (int j = 0; j < 2; ++j) {
            const int oct = (2 * w + j) * 4 + quad;
            #pragma unroll
            for (int mt = 0; mt < 2; ++mt)
                A1[j][mt] = ld_cg(r1p + oct * 256 + (mt * 16 + am) * 8);
        }
        f16x8 ax[2];
        if (w < 4) {
            const int ts = (s < TDIM) ? s : (TDIM - 1);
            const f16* xb = xP + (size_t)ts * BDIM * KIN;
            #pragma unroll
            for (int mt = 0; mt < 2; ++mt)
                ax[mt] = *(const f16x8*)(xb + (size_t)(b0 + mt * 16 + am) * KIN + w * 32 + kq);
        }
        VM_DRAIN();
        __builtin_amdgcn_sched_barrier(0);

        // ---- phase 1 (layer1) + layer2-Wih1 part (both consume A1) ----
        f32x4 acc[2][2], acc2[2][2];
        #pragma unroll
        for (int mt = 0; mt < 2; ++mt)
            #pragma unroll
            for (int nt = 0; nt < 2; ++nt) {
                acc[mt][nt]  = (f32x4){0.f, 0.f, 0.f, 0.f};
                acc2[mt][nt] = (f32x4){0.f, 0.f, 0.f, 0.f};
            }
        #pragma unroll
        for (int j = 0; j < 2; ++j)
            #pragma unroll
            for (int nt = 0; nt < 2; ++nt)
                #pragma unroll
                for (int mt = 0; mt < 2; ++mt) {
                    acc[mt][nt]  = MFMA16(A1[j][mt], B1h[j][nt], acc[mt][nt]);
                    acc2[mt][nt] = MFMA16(A1[j][mt], B2i[j][nt], acc2[mt][nt]);
                }
        if (w < 4)
            #pragma unroll
            for (int nt = 0; nt < 2; ++nt)
                #pragma unroll
                for (int mt = 0; mt < 2; ++mt)
                    acc[mt][nt] = MFMA16(ax[mt], B1x[nt], acc[mt][nt]);

        // ---- phase-1 fold: single pass, 64 slots = w*4 + mt*2 + nt ----
        #pragma unroll
        for (int mt = 0; mt < 2; ++mt)
            #pragma unroll
            for (int nt = 0; nt < 2; ++nt)
                *(f32x4*)&red[(w * 4 + mt * 2 + nt) * 324 + n * 20 + quad * 4] = acc[mt][nt];
        __syncthreads();   // S2

        // ---- reduce1: owners sum 16 partials -> h1 into LDS; w15 polls tagB ----
        if (w < 4 && s < TDIM) {
            float g4[4];
            #pragma unroll
            for (int g = 0; g < 4; ++g) {
                float sum = bias1[g];
                #pragma unroll
                for (int pp = 0; pp < 16; ++pp)
                    sum += red[(pp * 4 + mtO * 2 + ntO) * 324 + (nbO + g) * 20 + qmO];
                g4[g] = sum;
            }
            float ig = sigm(g4[0]), fg = sigm(g4[1]);
            float gg = tanhf(g4[2]), og = sigm(g4[3]);
            c1 = fg * c1 + ig * gg;
            hbuf1[b32O * 8 + cO] = (f16)(og * tanhf(c1));
        }
        // wait for h2^(s-2): published end of superstep s-1 -> slack = early body
        if (w == 15) tag_poll128(tagB + bg * 128, lane, (unsigned)s);
        __syncthreads();   // S4: hbuf1 ready, tagB satisfied, red(phase1) free

        // ---- wave 8: issue h1 publish store (drain overlapped with A2 loads) ----
        if (w == 8 && s < TDIM) {
            uint2 v = *(const uint2*)&hbuf1[lane * 4];
            st_cg8(ring1 + (size_t)(s & 1) * FRAME + bg * SUBF + cg * 256 + lane * 4, v);
        }

        // ---- A2 fragments of h2^(s-2) (tagB confirmed before S4) ----
        f16x8 A2[2][2];
        #pragma unroll
        for (int j = 0; j < 2; ++j) {
            const int oct = (2 * w + j) * 4 + quad;
            #pragma unroll
            for (int mt = 0; mt < 2; ++mt)
                A2[j][mt] = ld_cg(r2p + oct * 256 + (mt * 16 + am) * 8);
        }
        // wave 8: 5 outstanding (store oldest, 4 loads) -> vmcnt(4) = store done
        if (w == 8 && s < TDIM) {
            asm volatile("s_waitcnt vmcnt(4)" ::: "memory");
            if (lane == 0) tag_pub(tagA + bid, (unsigned)(s + 2));
        }
        VM_WAIT4(A2[0][0], A2[0][1], A2[1][0], A2[1][1]);
        __builtin_amdgcn_sched_barrier(0);

        #pragma unroll
        for (int j = 0; j < 2; ++j)
            #pragma unroll
            for (int nt = 0; nt < 2; ++nt)
                #pragma unroll
                for (int mt = 0; mt < 2; ++mt)
                    acc2[mt][nt] = MFMA16(A2[j][mt], B2h[j][nt], acc2[mt][nt]);

        // ---- phase-2 fold: single pass ----
        #pragma unroll
        for (int mt = 0; mt < 2; ++mt)
            #pragma unroll
            for (int nt = 0; nt < 2; ++nt)
                *(f32x4*)&red[(w * 4 + mt * 2 + nt) * 324 + n * 20 + quad * 4] = acc2[mt][nt];
        __syncthreads();   // S5

        // ---- reduce2: owners sum 16 partials -> h2 into LDS ----
        if (w < 4 && s >= 1) {
            float g4[4];
            #pragma unroll
            for (int g = 0; g < 4; ++g) {
                float sum = bias2[g];
                #pragma unroll
                for (int pp = 0; pp < 16; ++pp)
                    sum += red[(pp * 4 + mtO * 2 + ntO) * 324 + (nbO + g) * 20 + qmO];
                g4[g] = sum;
            }
            float ig = sigm(g4[0]), fg = sigm(g4[1]);
            float gg = tanhf(g4[2]), og = sigm(g4[3]);
            c2 = fg * c2 + ig * gg;
            hbuf2[b32O * 8 + cO] = (f16)(og * tanhf(c2));
        }
        __syncthreads();   // S7: hbuf2 ready

        // ---- wave 9: coalesced h2 publish + tag (drain overlaps next-top polls) ----
        if (w == 9 && s >= 1) {
            uint2 v = *(const uint2*)&hbuf2[lane * 4];
            st_cg8(ring2 + (size_t)((s + 1) & 1) * FRAME + bg * SUBF + cg * 256 + lane * 4, v);
            VM_DRAIN();
            if (lane == 0) tag_pub(tagB + bid, (unsigned)(s + 1));
        }
    }
    // final h2^{(511)} is in ring2 frame 1
}

// ---------------------------------------------------------------------------
// out[b] = dot(h2[b, :], fc_w) + fc_b.  h2 in subframe/octet layout:
//   idx(k, b) = (b>>5)*SUBF + (k>>3)*256 + (b&31)*8 + (k&7)
// ---------------------------------------------------------------------------
__global__ void fc_kernel(const f16* __restrict__ h2f,
                          const float* __restrict__ fcw,
                          const float* __restrict__ fcb,
                          float* __restrict__ out) {
    __shared__ float red[256];
    const int tid = threadIdx.x;
    const int b = tid >> 2, q = tid & 3;
    const int base = (b >> 5) * SUBF + (b & 31) * 8;
    float s = 0.f;
    for (int oct = q * 32; oct < (q + 1) * 32; ++oct) {
        f16x8 v = *(const f16x8*)(h2f + base + oct * 256);
        #pragma unroll
        for (int j = 0; j < 8; ++j)
            s = fmaf((float)v[j], fcw[oct * 8 + j], s);
    }
    red[tid] = s;
    __syncthreads();
    if (q == 0)
        out[b] = red[tid] + red[tid + 1] + red[tid + 2] + red[tid + 3] + fcb[0];
}

// ---------------------------------------------------------------------------
extern "C" void kernel_launch(void* const* d_in, const int* in_sizes, int n_in,
                              void* d_out, int out_size, void* d_ws, size_t ws_size,
                              hipStream_t stream) {
    const float* x    = (const float*)d_in[0];
    const float* Wih0 = (const float*)d_in[1];
    const float* Whh0 = (const float*)d_in[2];
    const float* bih0 = (const float*)d_in[3];
    const float* bhh0 = (const float*)d_in[4];
    const float* Wih1 = (const float*)d_in[5];
    const float* Whh1 = (const float*)d_in[6];
    const float* bih1 = (const float*)d_in[7];
    const float* bhh1 = (const float*)d_in[8];
    const float* fcw  = (const float*)d_in[9];
    const float* fcb  = (const float*)d_in[10];
    float* out = (float*)d_out;

    // workspace (halfs): xP | Wc0 | Wh0 | Wc1 | Wh1 | ring1 | ring2 | tags
    f16* xPd   = (f16*)d_ws;
    f16* Wc0   = xPd + (size_t)TDIM * BDIM * KIN;
    f16* Wh0   = Wc0 + (size_t)4 * HDIM * KIN;
    f16* Wc1   = Wh0 + (size_t)4 * HDIM * HDIM;
    f16* Wh1   = Wc1 + (size_t)4 * HDIM * HDIM;
    f16* ring1 = Wh1 + (size_t)4 * HDIM * HDIM;
    f16* ring2 = ring1 + 2 * FRAME;
    unsigned* tagA = (unsigned*)(ring2 + 2 * FRAME);
    unsigned* tagB = tagA + 512;      // 2 KB apart

    hipMemsetAsync(tagA, 0, 4096, stream);
    {
        int n2 = 4 * HDIM * KIN / 2;
        cvt_w<<<dim3((n2 + 255) / 256), dim3(256), 0, stream>>>(Wih0, Wc0, n2);
        n2 = 4 * HDIM * HDIM / 2;
        cvt_w<<<dim3((n2 + 255) / 256), dim3(256), 0, stream>>>(Whh0, Wh0, n2);
        cvt_w<<<dim3((n2 + 255) / 256), dim3(256), 0, stream>>>(Whh1, Wh1, n2);
        cvt_w<<<dim3((n2 + 255) / 256), dim3(256), 0, stream>>>(Wih1, Wc1, n2);
    }
    {
        int np = TDIM * BDIM * (KIN / 2);
        cvt_x<<<dim3((np + 255) / 256), dim3(256), 0, stream>>>(x, xPd);
    }

    void* args[13];
    args[0]  = (void*)&xPd;
    args[1]  = (void*)&Wc0;
    args[2]  = (void*)&Wh0;
    args[3]  = (void*)&bih0;
    args[4]  = (void*)&bhh0;
    args[5]  = (void*)&Wc1;
    args[6]  = (void*)&Wh1;
    args[7]  = (void*)&bih1;
    args[8]  = (void*)&bhh1;
    args[9]  = (void*)&ring1;
    args[10] = (void*)&ring2;
    args[11] = (void*)&tagA;
    args[12] = (void*)&tagB;
    hipLaunchCooperativeKernel(reinterpret_cast<void*>(lstm_fused), dim3(NBLK), dim3(NTHR),
                               args, 0, stream);

    fc_kernel<<<dim3(1), dim3(256), 0, stream>>>(ring2 + FRAME, fcw, fcb, out);
}